// Round 4
// baseline (245.179 us; speedup 1.0000x reference)
//
#include <hip/hip_runtime.h>
#include <cstdint>
#include <cstddef>

#define DD 128
#define KK 32
constexpr float EPS = 1e-8f;

typedef __bf16 bf16x8 __attribute__((ext_vector_type(8)));
typedef float f32x4 __attribute__((ext_vector_type(4)));

__device__ __forceinline__ unsigned short f2bf(float x) {
    union { float f; uint32_t u; } v; v.f = x;
    uint32_t r = v.u + 0x7FFFu + ((v.u >> 16) & 1u);   // RNE
    return (unsigned short)(r >> 16);
}
__device__ __forceinline__ float bflo(uint32_t w) {
    union { uint32_t u; float f; } v; v.u = w << 16; return v.f;
}
__device__ __forceinline__ float bfhi(uint32_t w) {
    union { uint32_t u; float f; } v; v.u = w & 0xFFFF0000u; return v.f;
}

#define ASYNC_COPY16(g, l) \
    __builtin_amdgcn_global_load_lds((const __attribute__((address_space(1))) void*)(g), \
                                     (__attribute__((address_space(3))) void*)(l), 16, 0, 0)

// ---------------- prep kernel: all format conversions in ONE launch ---------
// blocks [0, cvt_half)          : x1 -> X1f   (bf16 A-fragment layout)
// blocks [cvt_half, 2*cvt_half) : x2 -> X2f
// blocks [2c, 2c+wf_half)       : W1 -> W1f   (bf16 B-fragment layout)
// blocks [2c+wf_half, ...)      : W2 -> W2f
// Xf[rg][c][m][8]: row = rg*16+m, d = c*8+j  -> off = rg*2048 + c*128 + m*8
// Wf[k][eg][c][m][8]: W[k][d=c*8+j][e=eg*16+m]
__global__ __launch_bounds__(256) void prep_kernel(
    const float* __restrict__ x1, const float* __restrict__ x2,
    const float* __restrict__ W1, const float* __restrict__ W2,
    __bf16* __restrict__ X1f, __bf16* __restrict__ X2f,
    __bf16* __restrict__ W1f, __bf16* __restrict__ W2f,
    int cvt_half, int wf_half)
{
    int bb = blockIdx.x;
    if (bb < 2 * cvt_half) {
        const float* src; __bf16* dst;
        if (bb >= cvt_half) { src = x2; dst = X2f; bb -= cvt_half; }
        else                { src = x1; dst = X1f; }
        int idx = bb * 256 + threadIdx.x;
        int row = idx >> 4, c = idx & 15;
        const float* p = src + (size_t)row * DD + c * 8;
        float4 f0 = *reinterpret_cast<const float4*>(p);
        float4 f1 = *reinterpret_cast<const float4*>(p + 4);
        ushort4 o0, o1;
        o0.x = f2bf(f0.x); o0.y = f2bf(f0.y); o0.z = f2bf(f0.z); o0.w = f2bf(f0.w);
        o1.x = f2bf(f1.x); o1.y = f2bf(f1.y); o1.z = f2bf(f1.z); o1.w = f2bf(f1.w);
        size_t off = (size_t)(row >> 4) * 2048 + (size_t)c * 128 + (size_t)(row & 15) * 8;
        *reinterpret_cast<ushort4*>(dst + off)     = o0;
        *reinterpret_cast<ushort4*>(dst + off + 4) = o1;
    } else {
        bb -= 2 * cvt_half;
        const float* W; __bf16* Wf;
        if (bb >= wf_half) { W = W2; Wf = W2f; bb -= wf_half; }
        else               { W = W1; Wf = W1f; }
        int idx = bb * 256 + threadIdx.x;
        int m  = idx & 15;
        int c  = (idx >> 4) & 15;
        int eg = (idx >> 8) & 7;
        int k  = idx >> 11;
        const float* Wk = W + (size_t)k * DD * DD;
        int e = eg * 16 + m;
        ushort4 o0, o1;
        o0.x = f2bf(Wk[(size_t)(c * 8 + 0) * DD + e]);
        o0.y = f2bf(Wk[(size_t)(c * 8 + 1) * DD + e]);
        o0.z = f2bf(Wk[(size_t)(c * 8 + 2) * DD + e]);
        o0.w = f2bf(Wk[(size_t)(c * 8 + 3) * DD + e]);
        o1.x = f2bf(Wk[(size_t)(c * 8 + 4) * DD + e]);
        o1.y = f2bf(Wk[(size_t)(c * 8 + 5) * DD + e]);
        o1.z = f2bf(Wk[(size_t)(c * 8 + 6) * DD + e]);
        o1.w = f2bf(Wk[(size_t)(c * 8 + 7) * DD + e]);
        size_t off = ((size_t)(k * 8 + eg)) * 2048 + (size_t)c * 128 + (size_t)m * 8;
        *reinterpret_cast<ushort4*>(Wf + off)     = o0;
        *reinterpret_cast<ushort4*>(Wf + off + 4) = o1;
    }
}

// ---------------- main fused kernel ----------------
// 1D grid 8192, XCD-aware decode: xcd=b&7, k=(b>>3)&31 fast (output-line merge,
// W L2-resident per XCD), ntile = xcd*nt_per_xcd + (b>>8).
// Per block: stage W1f[k]+W2f[k] (64 KB) into LDS via global_load_lds, then a
// barrier-free K-loop (A from global/L2, B from LDS), then reduced epilogue.
struct EpiMem {
    float red[2][4][3][128];   // [col-half][lane-group][dot,n1,n2][row]
    float p2h[128];            // x2 . V[k][128:256] partial
};
union SMem {
    __bf16 w[2][16384];        // W1f[k], W2f[k] staged fragments (64 KB)
    EpiMem epi;                // reused after K-loop (union: 64 KB total)
};

__global__ __launch_bounds__(256, 2) void ntn_main(
    const __bf16* __restrict__ X1f, const __bf16* __restrict__ X2f,
    const __bf16* __restrict__ W1f, const __bf16* __restrict__ W2f,
    const float* __restrict__ V, const float* __restrict__ bias,
    float* __restrict__ out, int nt_per_xcd)
{
    __shared__ SMem smem;

    const int b     = blockIdx.x;
    const int xcd   = b & 7;
    const int j     = b >> 3;
    const int k     = j & 31;
    const int ntile = xcd * nt_per_xcd + (j >> 5);
    const int tid   = threadIdx.x;
    const int wave  = tid >> 6;
    const int lane  = tid & 63;
    const int m     = lane & 15;
    const int quad  = lane >> 4;
    const int h     = wave & 1;          // column half (0: e 0-63, 1: e 64-127)
    const int wrow  = (wave >> 1) * 64;  // row half

    // ---- stage W[k] (both tensors, fragment order) into LDS: 64 chunks x 1KB
    {
        const __bf16* wsrc = (wave < 2) ? (W1f + (size_t)k * 16384)
                                        : (W2f + (size_t)k * 16384);
        const char* gsrc = (const char*)wsrc + (size_t)(wave & 1) * 16384 + (size_t)lane * 16;
        char* lbase = (char*)&smem.w[0][0] + (size_t)wave * 16384;
        #pragma unroll
        for (int i = 0; i < 16; ++i)
            ASYNC_COPY16(gsrc + i * 1024, lbase + i * 1024);
    }

    f32x4 acc1[4][4], acc2[4][4];
    #pragma unroll
    for (int i = 0; i < 4; ++i)
        #pragma unroll
        for (int jj = 0; jj < 4; ++jj) {
            acc1[i][jj] = f32x4{0.f, 0.f, 0.f, 0.f};
            acc2[i][jj] = f32x4{0.f, 0.f, 0.f, 0.f};
        }

    const int rgb = ntile * 8 + (wrow >> 4);
    const int egb = h * 4;

    __syncthreads();   // drains the global_load_lds queue (vmcnt) + barrier

    #pragma unroll
    for (int ks = 0; ks < 4; ++ks) {
        bf16x8 a1[4], a2[4];
        #pragma unroll
        for (int rt = 0; rt < 4; ++rt) {
            const size_t off = (size_t)(rgb + rt) * 2048 + ks * 512 + lane * 8;
            a1[rt] = *reinterpret_cast<const bf16x8*>(X1f + off);
            a2[rt] = *reinterpret_cast<const bf16x8*>(X2f + off);
        }
        #pragma unroll
        for (int et = 0; et < 4; ++et) {
            const size_t boff = (size_t)(egb + et) * 2048 + ks * 512 + lane * 8;
            bf16x8 b1 = *reinterpret_cast<const bf16x8*>(&smem.w[0][boff]);
            bf16x8 b2 = *reinterpret_cast<const bf16x8*>(&smem.w[1][boff]);
            #pragma unroll
            for (int rt = 0; rt < 4; ++rt) {
                acc1[rt][et] = __builtin_amdgcn_mfma_f32_16x16x32_bf16(a1[rt], b1, acc1[rt][et], 0, 0, 0);
                acc2[rt][et] = __builtin_amdgcn_mfma_f32_16x16x32_bf16(a2[rt], b2, acc2[rt][et], 0, 0, 0);
            }
        }
    }

    __syncthreads();   // all waves done reading smem.w -> safe to reuse as epi

    // ---- epilogue: vector products + 2-step butterfly + 4-lane partials ----
    #pragma unroll
    for (int rt = 0; rt < 4; ++rt) {
        f32x4 pd = {0.f, 0.f, 0.f, 0.f};
        f32x4 q1 = {0.f, 0.f, 0.f, 0.f};
        f32x4 q2 = {0.f, 0.f, 0.f, 0.f};
        #pragma unroll
        for (int et = 0; et < 4; ++et) {
            pd += acc1[rt][et] * acc2[rt][et];
            q1 += acc1[rt][et] * acc1[rt][et];
            q2 += acc2[rt][et] * acc2[rt][et];
        }
        #pragma unroll
        for (int off = 1; off <= 2; off <<= 1) {
            f32x4 t;
            #pragma unroll
            for (int c = 0; c < 4; ++c) t[c] = __shfl_xor(pd[c], off, 64);
            pd += t;
            #pragma unroll
            for (int c = 0; c < 4; ++c) t[c] = __shfl_xor(q1[c], off, 64);
            q1 += t;
            #pragma unroll
            for (int c = 0; c < 4; ++c) t[c] = __shfl_xor(q2[c], off, 64);
            q2 += t;
        }
        if ((m & 3) == 0) {
            const int grp = m >> 2;
            const int rb  = wrow + rt * 16 + quad * 4;
            *reinterpret_cast<f32x4*>(&smem.epi.red[h][grp][0][rb]) = pd;
            *reinterpret_cast<f32x4*>(&smem.epi.red[h][grp][1][rb]) = q1;
            *reinterpret_cast<f32x4*>(&smem.epi.red[h][grp][2][rb]) = q2;
        }
    }

    // ---- part2: all 256 threads compute half of xcat[n].V[k] for one row ---
    const int row = tid & 127;
    const int rg  = ntile * 8 + (row >> 4);
    const size_t cb = (size_t)rg * 2048 + (size_t)(row & 15) * 8;
    const __bf16* Xsrc = (tid < 128) ? X1f : X2f;
    const float*  Vp   = V + (size_t)k * 256 + ((tid < 128) ? 0 : 128);
    float p2 = 0.f;
    #pragma unroll
    for (int c = 0; c < 16; ++c) {
        uint4 u = *reinterpret_cast<const uint4*>(Xsrc + cb + c * 128);
        float4 v0 = *reinterpret_cast<const float4*>(Vp + c * 8);
        float4 v1 = *reinterpret_cast<const float4*>(Vp + c * 8 + 4);
        p2 += bflo(u.x) * v0.x + bfhi(u.x) * v0.y
            + bflo(u.y) * v0.z + bfhi(u.y) * v0.w
            + bflo(u.z) * v1.x + bfhi(u.z) * v1.y
            + bflo(u.w) * v1.z + bfhi(u.w) * v1.w;
    }
    if (tid >= 128) smem.epi.p2h[row] = p2;
    __syncthreads();

    if (tid < 128) {
        float dot = 0.f, s1 = 0.f, s2 = 0.f;
        #pragma unroll
        for (int hg = 0; hg < 8; ++hg) {
            const int hh = hg >> 2, gg = hg & 3;
            dot += smem.epi.red[hh][gg][0][row];
            s1  += smem.epi.red[hh][gg][1][row];
            s2  += smem.epi.red[hh][gg][2][row];
        }
        float n1 = fmaxf(sqrtf(s1), EPS);
        float n2 = fmaxf(sqrtf(s2), EPS);
        float part1 = dot / (n1 * n2);
        float tot = part1 + p2 + smem.epi.p2h[row] + bias[k];
        out[((size_t)ntile * 128 + row) * KK + k] = fmaxf(tot, 0.f);
    }
}

extern "C" void kernel_launch(void* const* d_in, const int* in_sizes, int n_in,
                              void* d_out, int out_size, void* d_ws, size_t ws_size,
                              hipStream_t stream) {
    const float* x1 = (const float*)d_in[0];
    const float* x2 = (const float*)d_in[1];
    const float* W1 = (const float*)d_in[2];
    const float* W2 = (const float*)d_in[3];
    const float* V  = (const float*)d_in[4];
    const float* b  = (const float*)d_in[5];
    float* out = (float*)d_out;

    const int N = in_sizes[0] / DD;   // 32768

    __bf16* X1f = (__bf16*)d_ws;
    __bf16* X2f = X1f + (size_t)N * DD;
    __bf16* W1f = X2f + (size_t)N * DD;
    __bf16* W2f = W1f + (size_t)KK * DD * DD;

    const int cvt_half = N * 16 / 256;            // 2048
    const int wf_half  = KK * DD * DD / 8 / 256;  // 256
    prep_kernel<<<2 * cvt_half + 2 * wf_half, 256, 0, stream>>>(
        x1, x2, W1, W2, X1f, X2f, W1f, W2f, cvt_half, wf_half);

    const int ntiles = N / 128;
    ntn_main<<<ntiles * KK, 256, 0, stream>>>(X1f, X2f, W1f, W2f, V, b, out, ntiles / 8);
}